// Round 1
// 9.831 us; speedup vs baseline: 1.1093x; 1.1093x over previous
//
#include <hip/hip_runtime.h>

// QuantumDifficultyAdjuster — closed-form collapse of the product-state circuit.
//
// out_h = prod_{q=0}^{2h} z_q,  z_q = cos(th_q1)*cos(x_q) - sin(th_q1)*cos(th_q0)*sin(x_q)
// y = q_out @ fc_w.T + fc_b
//
// v2: 4 rows per thread.
//  - stores become 3x float4 (48B/thread, 16B-aligned) instead of 3 scalar
//    dwords at stride 12 -> no partially-written sectors, 1/3 store instrs.
//  - the 21 wave-uniform theta transcendentals are computed once per thread
//    and amortized over 4 rows (was recomputed per row).
//  - 8 independent float4 loads per thread give address-stream depth to
//    hide HBM/L2 latency at low occupancy.
// block=64, grid=512 -> 512 waves spread over all 256 CUs (2 waves/CU).
__global__ __launch_bounds__(64) void qda_kernel(
    const float* __restrict__ x,      // (B, 8)
    const float* __restrict__ theta,  // (24,)
    const float* __restrict__ fc_w,   // (3, 4) row-major
    const float* __restrict__ fc_b,   // (3,)
    float* __restrict__ out,          // (B, 3)
    int batch)
{
    const int i = blockIdx.x * blockDim.x + threadIdx.x;
    const int base = i * 4;                 // first row of this thread's quad
    if (base >= batch) return;

    // ---- wave-uniform, amortized over 4 rows ----
    float A[7], Bc[7];
#pragma unroll
    for (int q = 0; q < 7; ++q) {
        float th0 = theta[3 * q + 0];       // scalar loads (wave-uniform)
        float th1 = theta[3 * q + 1];
        A[q]  = __cosf(th1);
        Bc[q] = __sinf(th1) * __cosf(th0);
    }
    const float w00 = fc_w[0], w01 = fc_w[1], w02 = fc_w[2],  w03 = fc_w[3];
    const float w10 = fc_w[4], w11 = fc_w[5], w12 = fc_w[6],  w13 = fc_w[7];
    const float w20 = fc_w[8], w21 = fc_w[9], w22 = fc_w[10], w23 = fc_w[11];
    const float b0 = fc_b[0], b1 = fc_b[1], b2 = fc_b[2];

    if (base + 4 <= batch) {
        // ---- fast path: 4 full rows, fully vectorized IO ----
        const float4* xp = reinterpret_cast<const float4*>(x + (size_t)base * 8);
        float xv[32];
#pragma unroll
        for (int k = 0; k < 8; ++k) {
            float4 v = xp[k];               // 8 independent 16B loads (ILP)
            xv[4 * k + 0] = v.x;
            xv[4 * k + 1] = v.y;
            xv[4 * k + 2] = v.z;
            xv[4 * k + 3] = v.w;
        }

        float y[12];
#pragma unroll
        for (int r = 0; r < 4; ++r) {
            float z[7];
#pragma unroll
            for (int q = 0; q < 7; ++q) {
                float s, c;
                __sincosf(xv[8 * r + q], &s, &c);
                z[q] = fmaf(A[q], c, -Bc[q] * s);
            }
            float h0 = z[0];
            float h1 = h0 * z[1] * z[2];
            float h2 = h1 * z[3] * z[4];
            float h3 = h2 * z[5] * z[6];
            y[3 * r + 0] = fmaf(w00, h0, fmaf(w01, h1, fmaf(w02, h2, fmaf(w03, h3, b0))));
            y[3 * r + 1] = fmaf(w10, h0, fmaf(w11, h1, fmaf(w12, h2, fmaf(w13, h3, b1))));
            y[3 * r + 2] = fmaf(w20, h0, fmaf(w21, h1, fmaf(w22, h2, fmaf(w23, h3, b2))));
        }

        float4* op = reinterpret_cast<float4*>(out + (size_t)base * 3);
        op[0] = make_float4(y[0], y[1], y[2],  y[3]);
        op[1] = make_float4(y[4], y[5], y[6],  y[7]);
        op[2] = make_float4(y[8], y[9], y[10], y[11]);
    } else {
        // ---- tail path (batch % 4 != 0): scalar per row ----
        for (int row = base; row < batch; ++row) {
            const float* xs = x + (size_t)row * 8;
            float z[7];
#pragma unroll
            for (int q = 0; q < 7; ++q) {
                float s, c;
                __sincosf(xs[q], &s, &c);
                z[q] = fmaf(A[q], c, -Bc[q] * s);
            }
            float h0 = z[0];
            float h1 = h0 * z[1] * z[2];
            float h2 = h1 * z[3] * z[4];
            float h3 = h2 * z[5] * z[6];
            float* op = out + (size_t)row * 3;
            op[0] = fmaf(w00, h0, fmaf(w01, h1, fmaf(w02, h2, fmaf(w03, h3, b0))));
            op[1] = fmaf(w10, h0, fmaf(w11, h1, fmaf(w12, h2, fmaf(w13, h3, b1))));
            op[2] = fmaf(w20, h0, fmaf(w21, h1, fmaf(w22, h2, fmaf(w23, h3, b2))));
        }
    }
}

extern "C" void kernel_launch(void* const* d_in, const int* in_sizes, int n_in,
                              void* d_out, int out_size, void* d_ws, size_t ws_size,
                              hipStream_t stream) {
    const float* x     = (const float*)d_in[0];
    const float* theta = (const float*)d_in[1];
    const float* fc_w  = (const float*)d_in[2];
    const float* fc_b  = (const float*)d_in[3];
    float* out = (float*)d_out;

    int batch = in_sizes[0] / 8;            // x is (B, 8)
    int nthreads = (batch + 3) / 4;         // 4 rows per thread
    int block = 64;
    int grid = (nthreads + block - 1) / block;
    qda_kernel<<<grid, block, 0, stream>>>(x, theta, fc_w, fc_b, out, batch);
}